// Round 15
// baseline (7095.211 us; speedup 1.0000x reference)
//
#include <hip/hip_runtime.h>

typedef _Float16 half8 __attribute__((ext_vector_type(8)));
typedef _Float16 half4_t __attribute__((ext_vector_type(4)));
typedef _Float16 half2_t __attribute__((ext_vector_type(2)));
typedef float f32x4 __attribute__((ext_vector_type(4)));
typedef float f32x2 __attribute__((ext_vector_type(2)));
typedef unsigned long long u64;
typedef unsigned int u32;

#define SCALE 0.03125f   // 1/sqrt(1024)

// workspace layout (bytes)
#define XZ_OFF   0ULL            // f16 [8192][2048]  33,554,432
#define RING_OFF 33554432ULL     // ring: 16 groups x 8 slots x 36,864 B (xbf reused)
#define XBF_OFF  33554432ULL     // x f16 (pre-scan only; overlays ring)
#define WXZ_OFF  50331648ULL     // f16 [2048][1024]   4,194,304
#define WH_OFF   54525952ULL     // f16 [1024][1024]   2,097,152
#define WW_OFF   56623104ULL     // f16 [1024][1024]   2,097,152
#define VOTE_OFF 58720256ULL     // u32 [256][4] = 4096   (memset'd)
#define SEN_OFF  58724352ULL     // u32 [256][32] (128B stride) = 32768 (memset'd)

// ring slot internals: per (group, slot)
#define SLOTB 36864ULL
#define R_WVP 0        // f16 [16 slices][1024]  32,768  (packed half2 per thread)
#define R_H   32768    // f16 [1024]              2,048

union Pk2 { u64 u[2]; half8 h8; };
union PkW { u32 u; half2_t h; };

// ---- transport helpers: uniform `mall` flag picks MALL vs same-XCD L2 (proven) ----
__device__ __forceinline__ u64 ldq(const u64* p, bool mall) {
    return mall ? __hip_atomic_load(p, __ATOMIC_RELAXED, __HIP_MEMORY_SCOPE_AGENT) : *p;
}
__device__ __forceinline__ void stq(u64* p, u64 v, bool mall) {
    if (mall) __hip_atomic_store(p, v, __ATOMIC_RELAXED, __HIP_MEMORY_SCOPE_AGENT); else *p = v;
}
__device__ __forceinline__ u32 ldw(const u32* p, bool mall) {
    return mall ? __hip_atomic_load(p, __ATOMIC_RELAXED, __HIP_MEMORY_SCOPE_AGENT) : *p;
}
__device__ __forceinline__ void stw(u32* p, u32 v, bool mall) {
    if (mall) __hip_atomic_store(p, v, __ATOMIC_RELAXED, __HIP_MEMORY_SCOPE_AGENT); else *p = v;
}
// sentinels: relaxed AGENT atomics on 16 INDEPENDENT 128B-strided lines
__device__ __forceinline__ u32 ldsen(u32* p) {
    return __hip_atomic_load(p, __ATOMIC_RELAXED, __HIP_MEMORY_SCOPE_AGENT);
}
__device__ __forceinline__ void stsen(u32* p, u32 v) {
    __hip_atomic_store(p, v, __ATOMIC_RELAXED, __HIP_MEMORY_SCOPE_AGENT);
}

#define FDOT(a,b,acc) acc = __builtin_amdgcn_fdot2((a),(b),(acc),false)
__device__ __forceinline__ half2_t hp2(half8 v, int i) {
    half2_t r; r[0] = v[2*i]; r[1] = v[2*i+1]; return r;
}

__global__ void cvt_kernel(const float* __restrict__ in, _Float16* __restrict__ o, int n4) {
    int i = blockIdx.x * 256 + threadIdx.x;
    if (i < n4) {
        f32x4 v = ((const f32x4*)in)[i];
        half4_t h;
        h[0] = (_Float16)v[0]; h[1] = (_Float16)v[1];
        h[2] = (_Float16)v[2]; h[3] = (_Float16)v[3];
        ((half4_t*)o)[i] = h;
    }
}

// xz[m][n] = sum_k x[m][k] * Wxz[n][k];  M=8192, N=2048, K=1024  (unchanged, proven)
__launch_bounds__(256, 1)
__global__ void gemm_xz(const _Float16* __restrict__ A,
                        const _Float16* __restrict__ Bw,
                        _Float16* __restrict__ C) {
    __shared__ _Float16 As[128 * 40];
    __shared__ _Float16 Bs[128 * 40];
    const int tid = threadIdx.x;
    const int m0 = blockIdx.y * 128, n0 = blockIdx.x * 128;
    const int w = tid >> 6, lane = tid & 63;
    const int mw = (w >> 1) * 64, nw = (w & 1) * 64;
    const int row = lane & 15, q = lane >> 4;
    f32x4 acc[4][4];
    #pragma unroll
    for (int mt = 0; mt < 4; mt++)
        #pragma unroll
        for (int nt = 0; nt < 4; nt++)
            acc[mt][nt] = (f32x4){0.f, 0.f, 0.f, 0.f};

    for (int k0 = 0; k0 < 1024; k0 += 32) {
        __syncthreads();
        for (int cc = tid; cc < 512; cc += 256) {
            int r = cc >> 2, kc = (cc & 3) * 8;
            *(half8*)(&As[r * 40 + kc]) = *(const half8*)(&A[(size_t)(m0 + r) * 1024 + k0 + kc]);
            *(half8*)(&Bs[r * 40 + kc]) = *(const half8*)(&Bw[(size_t)(n0 + r) * 1024 + k0 + kc]);
        }
        __syncthreads();
        half8 af[4], bf[4];
        #pragma unroll
        for (int mt = 0; mt < 4; mt++) af[mt] = *(const half8*)(&As[(mw + mt * 16 + row) * 40 + q * 8]);
        #pragma unroll
        for (int nt = 0; nt < 4; nt++) bf[nt] = *(const half8*)(&Bs[(nw + nt * 16 + row) * 40 + q * 8]);
        #pragma unroll
        for (int mt = 0; mt < 4; mt++)
            #pragma unroll
            for (int nt = 0; nt < 4; nt++)
                acc[mt][nt] = __builtin_amdgcn_mfma_f32_16x16x32_f16(af[mt], bf[nt], acc[mt][nt], 0, 0, 0);
    }
    #pragma unroll
    for (int mt = 0; mt < 4; mt++)
        #pragma unroll
        for (int nt = 0; nt < 4; nt++)
            #pragma unroll
            for (int r = 0; r < 4; r++) {
                int gm = m0 + mw + mt * 16 + q * 4 + r;
                int gn = n0 + nw + nt * 16 + row;
                C[(size_t)gm * 2048 + gn] = (_Float16)acc[mt][nt][r];
            }
}

// Batch-partitioned persistent scan — R10/R13 512-thread structure + linearity
// fusion (R8's experiment, re-run in the geometry with regalloc headroom).
// ONE fused 33-slot partials round: 0..15 wv.tape_old (write scores),
// 16..31 h.tape_old (q), 32 h.wv — own-h read direct from ring (pre-B1).
// Read scores: rs_n = (1-wa_n) q_n + wa_n (h.wv);  rv = sum ra(1-wa) tp_old
// + (sum ra wa) wv  (R6-verified algebra).  Barriers 7 -> 5.
__launch_bounds__(512, 2)
__global__ void scan_kernel(const _Float16* __restrict__ xz,   // [8192][2048] f16
                            const float* __restrict__ tape_in, // [16][16][1024]
                            const float* __restrict__ h_in,    // [16][1024]
                            const float* __restrict__ bh,      // [1024]
                            const _Float16* __restrict__ wh,   // [1024][1024] f16
                            const _Float16* __restrict__ ww,   // [1024][1024] f16
                            char* ring,                        // 16 groups x 8 slots x SLOTB
                            u32* sen,                          // [256][32]
                            u32* vote,                         // [256][4]
                            float* __restrict__ out) {
    const int bx = blockIdx.x;
    const int g = (bx & 7) * 2 + ((bx >> 3) & 1);   // batch group 0..15
    const int s = bx >> 4;                           // dim slice 0..15 (cols s*64..+63)
    const int tid = threadIdx.x;                     // 0..511
    const int lane = tid & 63;
    const int cc = tid >> 3, q = tid & 7;            // col-role: col cc (0..63), k-eighth q
    const int nn = tid >> 5, c32 = tid & 31;         // reducer role (16 rows x 32 threads)

    __shared__ __align__(16) _Float16 h_prev[1024];  // full h_{t-1}, f16 (matvec operand)
    __shared__ __align__(16) _Float16 h_own[64];     // own slice of h_t
    __shared__ __align__(16) float rv_l[1024];       // read_val (global dim order)
    __shared__ float p_l[512 * 35];                  // fused partials (slots 0..32)
    __shared__ float sc_l[33];                       // [0..15] wv.tape, [16..31] q, [32] h.wv
    __shared__ float pad_l[1100];                    // total LDS > 80 KiB: 1 block/CU
    __shared__ int sh_same;

    if (tid < 1100) { volatile float* vp = pad_l; vp[tid] = 0.f; }   // keep pad alive

    // ---- per-group XCC vote (memset-initialized) ----
    if (tid == 0) {
        u32 xcc;
        asm volatile("s_getreg_b32 %0, hwreg(HW_REG_XCC_ID)" : "=s"(xcc));
        xcc &= 7u;
        __hip_atomic_store(&vote[bx * 4], xcc + 1u, __ATOMIC_RELAXED, __HIP_MEMORY_SCOPE_AGENT);
        int same = 1; u32 ref = 0;
        for (int m = 0; m < 16; m++) {
            int mb = m * 16 + ((g & 1) << 3) + (g >> 1);   // group member blockIdx
            u32 v; int spin = 0;
            while ((v = __hip_atomic_load(&vote[mb * 4], __ATOMIC_RELAXED, __HIP_MEMORY_SCOPE_AGENT)) == 0u) {
                if (++spin > 1000000) { v = 0xFFFFFFFFu; break; }
                __builtin_amdgcn_s_sleep(2);
            }
            if (m == 0) ref = v;
            if (v != ref || v == 0xFFFFFFFFu) same = 0;
        }
        sh_same = same;
    }
    __syncthreads();
    const bool mall = (sh_same == 0);
    bool dead = false;

    // ---- weights (allocator may stream; proven hidden by 2-wave TLP) ----
    const int qx = q << 1;
    half8 whr[16];   // Wh[col s*64+cc][k-eighth q], chunk order xor'd (bank-spread)
    {
        const _Float16* wp = wh + (size_t)(s * 64 + cc) * 1024 + q * 128;
        #pragma unroll
        for (int jj = 0; jj < 16; jj++)
            whr[jj] = *(const half8*)(wp + (((jj ^ qx) & 15) * 8));
    }
    half8 wwr[2][8]; // Ww rows 2*tid..+1, cols own 64 (row-slice for wvp partials)
    {
        const _Float16* wp = ww + (size_t)(tid * 2) * 1024 + s * 64;
        #pragma unroll
        for (int jj = 0; jj < 2; jj++)
            #pragma unroll
            for (int kk = 0; kk < 8; kk++)
                wwr[jj][kk] = *(const half8*)(wp + jj * 1024 + kk * 8);
    }
    // ---- replicated tape in registers: dims 2*tid..+1 for all 16 rows ----
    f32x2 tp[16];
    #pragma unroll
    for (int n = 0; n < 16; n++)
        tp[n] = *(const f32x2*)(&tape_in[(size_t)(g * 16 + n) * 1024 + tid * 2]);
    const float bhc = bh[s * 64 + cc];

    // ---- prologue: own h0 (reg) + h0 into h_prev ----
    half2_t own2;
    {
        f32x2 h2 = *(const f32x2*)(&h_in[(size_t)g * 1024 + tid * 2]);
        half2_t hh; hh[0] = (_Float16)h2[0]; hh[1] = (_Float16)h2[1];
        own2 = hh;
        *(half2_t*)(&h_prev[tid * 2]) = hh;
    }
    __syncthreads();

    u32* senrow = sen + (size_t)(g * 16 + s) * 32;
    const int senb = g * 16;

    for (int t = 0; t <= 512; t++) {
        char* srd  = ring + (size_t)(g * 8 + ((t + 7) & 7)) * SLOTB;  // slot (t-1)&7
        char* spub = ring + (size_t)(g * 8 + (t & 7)) * SLOTB;        // slot t&7
        const bool havew = (t >= 1);
        // early x_proj / z prefetch (8-redundant over q; hides under poll)
        float xp = 0.f, zz = 0.f;
        if (t < 512) {
            size_t m = (size_t)(g * 512 + t) * 2048 + s * 64 + cc;
            xp = (float)xz[m];
            zz = (float)xz[m + 1024];
        }
        f32x2 wv2 = (f32x2){0.f, 0.f};
        if (havew) {
            // ---- the single sync of the step: 16 parallel sentinel lines ----
            if (!dead && lane < 16) {
                int spin = 0;
                while (ldsen(&sen[(size_t)(senb + lane) * 32]) < (u32)t) {
                    if (++spin > 2000000) { dead = true; break; }
                    __builtin_amdgcn_s_sleep(1);
                }
            }
            asm volatile("" ::: "memory");
            // own 2 dims of h_{t-1} direct from ring (pre-B1; h_prev not ready yet)
            { PkW u; u.u = ldw(&((const u32*)(srd + R_H))[tid], mall); own2 = u.h; }
            // gather full h_{t-1} -> h_prev (consumed post-B1 by the matvec)
            if (tid < 128) {
                const u64* Hp = (const u64*)(srd + R_H);
                Pk2 u;
                u.u[0] = ldq(&Hp[tid * 2], mall);
                u.u[1] = ldq(&Hp[tid * 2 + 1], mall);
                *(half8*)(&h_prev[tid * 8]) = u.h8;
            }
            // wv all-reduce: own 2 dims from 16 producer slices (f16 packed, 4B each)
            const u32* Wp = (const u32*)(srd + R_WVP);
            #pragma unroll
            for (int sl = 0; sl < 16; sl++) {
                PkW u; u.u = ldw(&Wp[sl * 512 + tid], mall);
                wv2[0] += (float)u.h[0]; wv2[1] += (float)u.h[1];
            }
        }
        // ---- fused 33-slot partials (tape = pre-write-(t-1) state) ----
        {
            float h0 = (float)own2[0], h1 = (float)own2[1];
            if (havew) {
                #pragma unroll
                for (int n = 0; n < 16; n++) {
                    f32x2 d = tp[n];
                    p_l[tid * 35 + n] = wv2[0]*d[0] + wv2[1]*d[1];
                }
                if (t < 512)
                    p_l[tid * 35 + 32] = h0*wv2[0] + h1*wv2[1];
            }
            if (t < 512) {
                #pragma unroll
                for (int n = 0; n < 16; n++) {
                    f32x2 d = tp[n];
                    p_l[tid * 35 + 16 + n] = h0*d[0] + h1*d[1];
                }
            }
        }
        __syncthreads();                                   // B1: p_l + h_prev ready
        // ---- single reduce round: group nn owns slots nn and 16+nn; nn==0 also 32 ----
        if (havew) {
            float sw = 0.f;
            #pragma unroll
            for (int m2 = 0; m2 < 16; m2++) sw += p_l[(c32 + 32 * m2) * 35 + nn];
            #pragma unroll
            for (int d2 = 1; d2 < 32; d2 <<= 1) sw += __shfl_xor(sw, d2, 32);
            if (c32 == 0) sc_l[nn] = sw;
            if (nn == 0 && t < 512) {
                float hw = 0.f;
                #pragma unroll
                for (int m2 = 0; m2 < 16; m2++) hw += p_l[(c32 + 32 * m2) * 35 + 32];
                #pragma unroll
                for (int d2 = 1; d2 < 32; d2 <<= 1) hw += __shfl_xor(hw, d2, 32);
                if (c32 == 0) sc_l[32] = hw;
            }
        }
        if (t < 512) {
            float sq = 0.f;
            #pragma unroll
            for (int m2 = 0; m2 < 16; m2++) sq += p_l[(c32 + 32 * m2) * 35 + 16 + nn];
            #pragma unroll
            for (int d2 = 1; d2 < 32; d2 <<= 1) sq += __shfl_xor(sq, d2, 32);
            if (c32 == 0) sc_l[16 + nn] = sq;
        }
        __syncthreads();                                   // B2: sc_l ready
        float wan[16];
        if (havew) {   // write softmax (redundant per thread)
            float e[16], mxw = -1e30f;
            #pragma unroll
            for (int n = 0; n < 16; n++) { e[n] = sc_l[n] * SCALE; mxw = fmaxf(mxw, e[n]); }
            float smw = 0.f;
            #pragma unroll
            for (int n = 0; n < 16; n++) { e[n] = __expf(e[n] - mxw); smw += e[n]; }
            float invw = 1.f / smw;
            #pragma unroll
            for (int n = 0; n < 16; n++) wan[n] = e[n] * invw;
        }
        if (t == 512) {   // finale: apply write of step 511, done
            #pragma unroll
            for (int n = 0; n < 16; n++) {
                f32x2 d = tp[n];
                d[0] += wan[n] * (wv2[0] - d[0]);
                d[1] += wan[n] * (wv2[1] - d[1]);
                tp[n] = d;
            }
            break;
        }
        // ---- read softmax via linearity (q from OLD tape) ----
        float r[16], mx = -1e30f;
        if (havew) {
            float hwv = sc_l[32];
            #pragma unroll
            for (int n = 0; n < 16; n++) {
                r[n] = ((1.f - wan[n]) * sc_l[16 + n] + wan[n] * hwv) * SCALE;
                mx = fmaxf(mx, r[n]);
            }
        } else {
            #pragma unroll
            for (int n = 0; n < 16; n++) { r[n] = sc_l[16 + n] * SCALE; mx = fmaxf(mx, r[n]); }
        }
        float sm = 0.f;
        #pragma unroll
        for (int n = 0; n < 16; n++) { r[n] = __expf(r[n] - mx); sm += r[n]; }
        float inv = 1.f / sm;
        // rv on own 2 dims from OLD tape: rv = sum ra(1-wa) tp_old + (sum ra wa) wv
        f32x2 rv2 = (f32x2){0.f, 0.f};
        if (havew) {
            float beta = 0.f;
            #pragma unroll
            for (int n = 0; n < 16; n++) {
                float ran = r[n] * inv;
                float c = ran * (1.f - wan[n]);
                rv2[0] += c * tp[n][0];
                rv2[1] += c * tp[n][1];
                beta += ran * wan[n];
            }
            rv2[0] += beta * wv2[0];
            rv2[1] += beta * wv2[1];
        } else {
            #pragma unroll
            for (int n = 0; n < 16; n++) {
                float ran = r[n] * inv;
                rv2[0] += ran * tp[n][0];
                rv2[1] += ran * tp[n][1];
            }
        }
        *(f32x2*)(&rv_l[tid * 2]) = rv2;
        // tape update (write of step t-1) — AFTER rv used the pre-update tape
        if (havew) {
            #pragma unroll
            for (int n = 0; n < 16; n++) {
                f32x2 d = tp[n];
                d[0] += wan[n] * (wv2[0] - d[0]);
                d[1] += wan[n] * (wv2[1] - d[1]);
                tp[n] = d;
            }
        }
        // Wh matvec (h_prev stable since B1); av carried in registers
        float a0 = 0.f, a1 = 0.f, a2 = 0.f, a3 = 0.f;
        #pragma unroll
        for (int jj = 0; jj < 16; jj++) {
            half8 hp8 = *(const half8*)(&h_prev[q * 128 + (((jj ^ qx) & 15) * 8)]);
            half8 wc = whr[jj];
            FDOT(hp2(wc,0), hp2(hp8,0), a0);
            FDOT(hp2(wc,1), hp2(hp8,1), a1);
            FDOT(hp2(wc,2), hp2(hp8,2), a2);
            FDOT(hp2(wc,3), hp2(hp8,3), a3);
        }
        float av = (a0 + a1) + (a2 + a3);
        av += __shfl_xor(av, 1);
        av += __shfl_xor(av, 2);
        av += __shfl_xor(av, 4);
        __syncthreads();                                       // B5: rv_l ready
        float rd = rv_l[s * 64 + cc];
        float hv = tanhf(av + xp + rd + bhc);
        float g2 = zz + rd + hv;
        float o = hv * g2 / (1.f + __expf(-g2));
        if (q == 0) h_own[cc] = (_Float16)hv;
        __syncthreads();                                       // B6: h_own ready
        // wvp partials: rows 2*tid..+1 over own 64 k (h_own broadcast reads)
        half8 hr[8];
        #pragma unroll
        for (int kk = 0; kk < 8; kk++) hr[kk] = *(const half8*)(&h_own[kk * 8]);
        float w0 = 0.f, w1 = 0.f;
        #pragma unroll
        for (int kk = 0; kk < 8; kk++) {
            half8 h8 = hr[kk];
            #pragma unroll
            for (int pp = 0; pp < 4; pp++) {
                FDOT(hp2(wwr[0][kk],pp), hp2(h8,pp), w0);
                FDOT(hp2(wwr[1][kk],pp), hp2(h8,pp), w1);
            }
        }
        {   // publish wvp (packed f16 half2, 4B) + h slice into slot t&7
            PkW wq;
            wq.h = (half2_t){(_Float16)w0, (_Float16)w1};
            stw(&((u32*)(spub + R_WVP))[s * 512 + tid], wq.u, mall);
            if (tid < 8) {
                Pk2 u; u.h8 = *(const half8*)(&h_own[tid * 8]);
                u64* Hp = (u64*)(spub + R_H);
                stq(&Hp[s * 16 + tid * 2],     u.u[0], mall);
                stq(&Hp[s * 16 + tid * 2 + 1], u.u[1], mall);
            }
        }
        __syncthreads();                                       // B7: vmcnt drain (h + wvp)
        if (tid == 0) stsen(senrow, (u32)(t + 1));
        // deferred out store (off the sentinel critical path)
        if (q == 0) out[(size_t)(g * 512 + t) * 1024 + s * 64 + cc] = o;
    }
    // ================= finale: write h_tape_final (slice 0 of each group) =================
    if (s == 0) {
        #pragma unroll
        for (int n = 0; n < 16; n++)
            *(f32x2*)(&out[8388608ULL + (size_t)(g * 16 + n) * 1024 + tid * 2]) = tp[n];
    }
}

extern "C" void kernel_launch(void* const* d_in, const int* in_sizes, int n_in,
                              void* d_out, int out_size, void* d_ws, size_t ws_size,
                              hipStream_t stream) {
    const float* x     = (const float*)d_in[0];
    const float* tape0 = (const float*)d_in[1];
    const float* h0    = (const float*)d_in[2];
    const float* Wh    = (const float*)d_in[3];
    const float* Wxz   = (const float*)d_in[4];
    const float* bh    = (const float*)d_in[5];
    const float* Ww    = (const float*)d_in[6];

    char* ws = (char*)d_ws;
    _Float16* xbf   = (_Float16*)(ws + XBF_OFF);
    _Float16* wxzbf = (_Float16*)(ws + WXZ_OFF);
    _Float16* whbf  = (_Float16*)(ws + WH_OFF);
    _Float16* wwbf  = (_Float16*)(ws + WW_OFF);
    _Float16* xzbf  = (_Float16*)(ws + XZ_OFF);
    char* ring      = ws + RING_OFF;
    u32* vote       = (u32*)(ws + VOTE_OFF);
    u32* sen        = (u32*)(ws + SEN_OFF);

    // vote (4 KB) + sentinels (32 KB): zeroed every launch
    hipMemsetAsync(ws + VOTE_OFF, 0, 4096 + 32768, stream);

    cvt_kernel<<<8192, 256, 0, stream>>>(x, xbf, 2097152);
    cvt_kernel<<<2048, 256, 0, stream>>>(Wxz, wxzbf, 524288);
    cvt_kernel<<<1024, 256, 0, stream>>>(Wh, whbf, 262144);
    cvt_kernel<<<1024, 256, 0, stream>>>(Ww, wwbf, 262144);

    gemm_xz<<<dim3(16, 64), 256, 0, stream>>>(xbf, wxzbf, xzbf);

    scan_kernel<<<256, 512, 0, stream>>>(xzbf, tape0, h0, bh, whbf, wwbf,
                                         ring, sen, vote, (float*)d_out);
}

// Round 17
// 2697.232 us; speedup vs baseline: 2.6306x; 2.6306x over previous
//
#include <hip/hip_runtime.h>

typedef _Float16 half8 __attribute__((ext_vector_type(8)));
typedef _Float16 half4_t __attribute__((ext_vector_type(4)));
typedef _Float16 half2_t __attribute__((ext_vector_type(2)));
typedef float f32x4 __attribute__((ext_vector_type(4)));
typedef float f32x2 __attribute__((ext_vector_type(2)));
typedef unsigned long long u64;
typedef unsigned int u32;

#define SCALE 0.03125f   // 1/sqrt(1024)

// workspace layout (bytes)
#define XZ_OFF   0ULL            // f16 [8192][2048]  33,554,432
#define RING_OFF 33554432ULL     // ring: 16 groups x 8 slots x 36,864 B (xbf reused)
#define XBF_OFF  33554432ULL     // x f16 (pre-scan only; overlays ring)
#define WXZ_OFF  50331648ULL     // f16 [2048][1024]   4,194,304
#define WH_OFF   54525952ULL     // f16 [1024][1024]   2,097,152
#define WW_OFF   56623104ULL     // f16 [1024][1024]   2,097,152
#define VOTE_OFF 58720256ULL     // u32 [256][4] = 4096   (memset'd)
#define SEN_OFF  58724352ULL     // u32 [256][32] (128B stride) = 32768 (memset'd)

// ring slot internals: per (group, slot)
#define SLOTB 36864ULL
#define R_WVP 0        // f16 [16 slices][1024]  32,768  (packed half2 per thread)
#define R_H   32768    // f16 [1024]              2,048

union Pk2 { u64 u[2]; half8 h8; };
union PkW { u32 u; half2_t h; };

// ---- transport helpers: uniform `mall` flag picks MALL vs same-XCD L2 (proven) ----
__device__ __forceinline__ u64 ldq(const u64* p, bool mall) {
    return mall ? __hip_atomic_load(p, __ATOMIC_RELAXED, __HIP_MEMORY_SCOPE_AGENT) : *p;
}
__device__ __forceinline__ void stq(u64* p, u64 v, bool mall) {
    if (mall) __hip_atomic_store(p, v, __ATOMIC_RELAXED, __HIP_MEMORY_SCOPE_AGENT); else *p = v;
}
__device__ __forceinline__ u32 ldw(const u32* p, bool mall) {
    return mall ? __hip_atomic_load(p, __ATOMIC_RELAXED, __HIP_MEMORY_SCOPE_AGENT) : *p;
}
__device__ __forceinline__ void stw(u32* p, u32 v, bool mall) {
    if (mall) __hip_atomic_store(p, v, __ATOMIC_RELAXED, __HIP_MEMORY_SCOPE_AGENT); else *p = v;
}
// sentinels: relaxed AGENT atomics on 16 INDEPENDENT 128B-strided lines
// (parallel-line poll; R9's single accumulating counter serialized 16 RMWs
// on one TCC line and cost ~+145us)
__device__ __forceinline__ u32 ldsen(u32* p) {
    return __hip_atomic_load(p, __ATOMIC_RELAXED, __HIP_MEMORY_SCOPE_AGENT);
}
__device__ __forceinline__ void stsen(u32* p, u32 v) {
    __hip_atomic_store(p, v, __ATOMIC_RELAXED, __HIP_MEMORY_SCOPE_AGENT);
}

#define FDOT(a,b,acc) acc = __builtin_amdgcn_fdot2((a),(b),(acc),false)
__device__ __forceinline__ half2_t hp2(half8 v, int i) {
    half2_t r; r[0] = v[2*i]; r[1] = v[2*i+1]; return r;
}

__global__ void cvt_kernel(const float* __restrict__ in, _Float16* __restrict__ o, int n4) {
    int i = blockIdx.x * 256 + threadIdx.x;
    if (i < n4) {
        f32x4 v = ((const f32x4*)in)[i];
        half4_t h;
        h[0] = (_Float16)v[0]; h[1] = (_Float16)v[1];
        h[2] = (_Float16)v[2]; h[3] = (_Float16)v[3];
        ((half4_t*)o)[i] = h;
    }
}

// xz[m][n] = sum_k x[m][k] * Wxz[n][k];  M=8192, N=2048, K=1024  (unchanged, proven)
__launch_bounds__(256, 1)
__global__ void gemm_xz(const _Float16* __restrict__ A,
                        const _Float16* __restrict__ Bw,
                        _Float16* __restrict__ C) {
    __shared__ _Float16 As[128 * 40];
    __shared__ _Float16 Bs[128 * 40];
    const int tid = threadIdx.x;
    const int m0 = blockIdx.y * 128, n0 = blockIdx.x * 128;
    const int w = tid >> 6, lane = tid & 63;
    const int mw = (w >> 1) * 64, nw = (w & 1) * 64;
    const int row = lane & 15, q = lane >> 4;
    f32x4 acc[4][4];
    #pragma unroll
    for (int mt = 0; mt < 4; mt++)
        #pragma unroll
        for (int nt = 0; nt < 4; nt++)
            acc[mt][nt] = (f32x4){0.f, 0.f, 0.f, 0.f};

    for (int k0 = 0; k0 < 1024; k0 += 32) {
        __syncthreads();
        for (int cc = tid; cc < 512; cc += 256) {
            int r = cc >> 2, kc = (cc & 3) * 8;
            *(half8*)(&As[r * 40 + kc]) = *(const half8*)(&A[(size_t)(m0 + r) * 1024 + k0 + kc]);
            *(half8*)(&Bs[r * 40 + kc]) = *(const half8*)(&Bw[(size_t)(n0 + r) * 1024 + k0 + kc]);
        }
        __syncthreads();
        half8 af[4], bf[4];
        #pragma unroll
        for (int mt = 0; mt < 4; mt++) af[mt] = *(const half8*)(&As[(mw + mt * 16 + row) * 40 + q * 8]);
        #pragma unroll
        for (int nt = 0; nt < 4; nt++) bf[nt] = *(const half8*)(&Bs[(nw + nt * 16 + row) * 40 + q * 8]);
        #pragma unroll
        for (int mt = 0; mt < 4; mt++)
            #pragma unroll
            for (int nt = 0; nt < 4; nt++)
                acc[mt][nt] = __builtin_amdgcn_mfma_f32_16x16x32_f16(af[mt], bf[nt], acc[mt][nt], 0, 0, 0);
    }
    #pragma unroll
    for (int mt = 0; mt < 4; mt++)
        #pragma unroll
        for (int nt = 0; nt < 4; nt++)
            #pragma unroll
            for (int r = 0; r < 4; r++) {
                int gm = m0 + mw + mt * 16 + q * 4 + r;
                int gn = n0 + nw + nt * 16 + row;
                C[(size_t)gm * 2048 + gn] = (_Float16)acc[mt][nt][r];
            }
}

// Batch-partitioned persistent scan — session-best R13 kernel (2695.8us
// measured; reproduced 2701-2707 in R10/R12/R14).  512-thread geometry
// (2 waves/SIMD hides LDS/L2 latency; bank-conflict-free), R2 dataflow
// (two reduce rounds — linearity fusion spills against the allocator's
// hard 128-VGPR budget: R8/R15), f16 wvp payload, 16 parallel 128B-strided
// sentinel lines, one sync/step.  Residual 12.6k cy/step is the serial
// sync+barrier chain (VALUBusy 53%, HBM 0.4%, no pipe saturated).
__launch_bounds__(512, 2)
__global__ void scan_kernel(const _Float16* __restrict__ xz,   // [8192][2048] f16
                            const float* __restrict__ tape_in, // [16][16][1024]
                            const float* __restrict__ h_in,    // [16][1024]
                            const float* __restrict__ bh,      // [1024]
                            const _Float16* __restrict__ wh,   // [1024][1024] f16
                            const _Float16* __restrict__ ww,   // [1024][1024] f16
                            char* ring,                        // 16 groups x 8 slots x SLOTB
                            u32* sen,                          // [256][32]
                            u32* vote,                         // [256][4]
                            float* __restrict__ out) {
    const int bx = blockIdx.x;
    const int g = (bx & 7) * 2 + ((bx >> 3) & 1);   // batch group 0..15
    const int s = bx >> 4;                           // dim slice 0..15 (cols s*64..+63)
    const int tid = threadIdx.x;                     // 0..511
    const int lane = tid & 63;
    const int cc = tid >> 3, q = tid & 7;            // col-role: col cc (0..63), k-eighth q
    const int nn = tid >> 5, c32 = tid & 31;         // reducer role (16 rows x 32 threads)

    __shared__ __align__(16) _Float16 h_prev[1024];  // full h_{t-1}, f16
    __shared__ __align__(16) _Float16 h_own[64];     // own slice of h_t
    __shared__ __align__(16) float rv_l[1024];       // read_val (global dim order)
    __shared__ float p_l[512 * 17];                  // score partials (pad 17)
    __shared__ float sc_l[16];
    __shared__ float pad_l[10000];                   // LDS > 80 KiB: force 1 block/CU
    __shared__ int sh_same;

    { volatile float* vp = pad_l; vp[tid] = 0.f; }   // keep pad alive

    // ---- per-group XCC vote (memset-initialized) ----
    if (tid == 0) {
        u32 xcc;
        asm volatile("s_getreg_b32 %0, hwreg(HW_REG_XCC_ID)" : "=s"(xcc));
        xcc &= 7u;
        __hip_atomic_store(&vote[bx * 4], xcc + 1u, __ATOMIC_RELAXED, __HIP_MEMORY_SCOPE_AGENT);
        int same = 1; u32 ref = 0;
        for (int m = 0; m < 16; m++) {
            int mb = m * 16 + ((g & 1) << 3) + (g >> 1);   // group member blockIdx
            u32 v; int spin = 0;
            while ((v = __hip_atomic_load(&vote[mb * 4], __ATOMIC_RELAXED, __HIP_MEMORY_SCOPE_AGENT)) == 0u) {
                if (++spin > 1000000) { v = 0xFFFFFFFFu; break; }
                __builtin_amdgcn_s_sleep(2);
            }
            if (m == 0) ref = v;
            if (v != ref || v == 0xFFFFFFFFu) same = 0;
        }
        sh_same = same;
    }
    __syncthreads();
    const bool mall = (sh_same == 0);
    bool dead = false;

    // ---- weights (allocator streams from L2; proven hidden by 2-wave TLP) ----
    const int qx = q << 1;
    half8 whr[16];   // Wh[col s*64+cc][k-eighth q], chunk order xor'd (bank-spread)
    {
        const _Float16* wp = wh + (size_t)(s * 64 + cc) * 1024 + q * 128;
        #pragma unroll
        for (int jj = 0; jj < 16; jj++)
            whr[jj] = *(const half8*)(wp + (((jj ^ qx) & 15) * 8));
    }
    half8 wwr[2][8]; // Ww rows 2*tid..+1, cols own 64 (row-slice for wvp partials)
    {
        const _Float16* wp = ww + (size_t)(tid * 2) * 1024 + s * 64;
        #pragma unroll
        for (int jj = 0; jj < 2; jj++)
            #pragma unroll
            for (int kk = 0; kk < 8; kk++)
                wwr[jj][kk] = *(const half8*)(wp + jj * 1024 + kk * 8);
    }
    // ---- replicated tape in registers: dims 2*tid..+1 for all 16 rows ----
    f32x2 tp[16];
    #pragma unroll
    for (int n = 0; n < 16; n++)
        tp[n] = *(const f32x2*)(&tape_in[(size_t)(g * 16 + n) * 1024 + tid * 2]);
    const float bhc = bh[s * 64 + cc];

    // ---- prologue: own h0 into h_prev ----
    {
        f32x2 h2 = *(const f32x2*)(&h_in[(size_t)g * 1024 + tid * 2]);
        half2_t hh; hh[0] = (_Float16)h2[0]; hh[1] = (_Float16)h2[1];
        *(half2_t*)(&h_prev[tid * 2]) = hh;
    }
    __syncthreads();

    u32* senrow = sen + (size_t)(g * 16 + s) * 32;
    const int senb = g * 16;

    for (int t = 0; t <= 512; t++) {
        char* srd  = ring + (size_t)(g * 8 + ((t + 7) & 7)) * SLOTB;  // slot (t-1)&7
        char* spub = ring + (size_t)(g * 8 + (t & 7)) * SLOTB;        // slot t&7
        const bool havew = (t >= 1);
        // early x_proj / z prefetch (8-redundant over q; hides under poll)
        float xp = 0.f, zz = 0.f;
        if (t < 512) {
            size_t m = (size_t)(g * 512 + t) * 2048 + s * 64 + cc;
            xp = (float)xz[m];
            zz = (float)xz[m + 1024];
        }
        f32x2 wv2 = (f32x2){0.f, 0.f};
        if (havew) {
            // ---- the single sync of the step: 16 parallel sentinel lines ----
            if (!dead && lane < 16) {
                int spin = 0;
                while (ldsen(&sen[(size_t)(senb + lane) * 32]) < (u32)t) {
                    if (++spin > 2000000) { dead = true; break; }
                    __builtin_amdgcn_s_sleep(1);
                }
            }
            asm volatile("" ::: "memory");
            // gather full h_{t-1} -> h_prev (read post-B1)
            if (tid < 128) {
                const u64* Hp = (const u64*)(srd + R_H);
                Pk2 u;
                u.u[0] = ldq(&Hp[tid * 2], mall);
                u.u[1] = ldq(&Hp[tid * 2 + 1], mall);
                *(half8*)(&h_prev[tid * 8]) = u.h8;
            }
            // wv all-reduce: own 2 dims from 16 producer slices (f16 packed, 4B each)
            const u32* Wp = (const u32*)(srd + R_WVP);
            #pragma unroll
            for (int sl = 0; sl < 16; sl++) {
                PkW u; u.u = ldw(&Wp[sl * 512 + tid], mall);
                wv2[0] += (float)u.h[0]; wv2[1] += (float)u.h[1];
            }
            // write-score partials (wv . tape entering step t-1)
            {
                float p[16];
                #pragma unroll
                for (int n = 0; n < 16; n++) {
                    f32x2 d = tp[n];
                    p[n] = wv2[0]*d[0] + wv2[1]*d[1];
                }
                #pragma unroll
                for (int n = 0; n < 16; n++) p_l[tid * 17 + n] = p[n];
            }
            __syncthreads();                                   // B1: p_l + h_prev ready
            {
                float scw = 0.f;
                #pragma unroll
                for (int m2 = 0; m2 < 16; m2++) scw += p_l[(c32 + 32 * m2) * 17 + nn];
                #pragma unroll
                for (int d2 = 1; d2 < 32; d2 <<= 1) scw += __shfl_xor(scw, d2, 32);
                if (c32 == 0) sc_l[nn] = scw;
            }
            __syncthreads();                                   // B2: sc_l ready
            {   // write softmax (redundant per thread) + lazy tape update
                float e[16], mxw = -1e30f;
                #pragma unroll
                for (int n = 0; n < 16; n++) { e[n] = sc_l[n] * SCALE; mxw = fmaxf(mxw, e[n]); }
                float smw = 0.f;
                #pragma unroll
                for (int n = 0; n < 16; n++) { e[n] = __expf(e[n] - mxw); smw += e[n]; }
                float invw = 1.f / smw;
                #pragma unroll
                for (int n = 0; n < 16; n++) {
                    float wan = e[n] * invw;
                    f32x2 d = tp[n];
                    d[0] += wan * (wv2[0] - d[0]);
                    d[1] += wan * (wv2[1] - d[1]);
                    tp[n] = d;
                }
            }
        }
        if (t == 512) break;   // finale: tape has write of step 511 applied

        // read-score partials (h_{t-1} . tape entering step t)
        {
            half2_t hh = *(const half2_t*)(&h_prev[tid * 2]);
            float h0 = (float)hh[0], h1 = (float)hh[1];
            float p[16];
            #pragma unroll
            for (int n = 0; n < 16; n++) {
                f32x2 d = tp[n];
                p[n] = h0*d[0] + h1*d[1];
            }
            #pragma unroll
            for (int n = 0; n < 16; n++) p_l[tid * 17 + n] = p[n];
        }
        __syncthreads();                                       // B3
        float sc = 0.f;
        #pragma unroll
        for (int m2 = 0; m2 < 16; m2++) sc += p_l[(c32 + 32 * m2) * 17 + nn];
        #pragma unroll
        for (int d2 = 1; d2 < 32; d2 <<= 1) sc += __shfl_xor(sc, d2, 32);
        if (c32 == 0) sc_l[nn] = sc;
        __syncthreads();                                       // B4
        float r[16], mx = -1e30f;
        #pragma unroll
        for (int n = 0; n < 16; n++) { r[n] = sc_l[n] * SCALE; mx = fmaxf(mx, r[n]); }
        float sm = 0.f;
        #pragma unroll
        for (int n = 0; n < 16; n++) { r[n] = __expf(r[n] - mx); sm += r[n]; }
        float inv = 1.f / sm;
        // read_val, own 2 dims (from register tape)
        f32x2 rv2 = (f32x2){0.f, 0.f};
        #pragma unroll
        for (int n = 0; n < 16; n++) {
            float ra = r[n] * inv;
            rv2[0] += ra * tp[n][0];
            rv2[1] += ra * tp[n][1];
        }
        *(f32x2*)(&rv_l[tid * 2]) = rv2;
        // Wh matvec (col-role): full h_{t-1} from LDS, xor'd chunk order
        float a0 = 0.f, a1 = 0.f, a2 = 0.f, a3 = 0.f;
        #pragma unroll
        for (int jj = 0; jj < 16; jj++) {
            half8 hp8 = *(const half8*)(&h_prev[q * 128 + (((jj ^ qx) & 15) * 8)]);
            half8 wc = whr[jj];
            FDOT(hp2(wc,0), hp2(hp8,0), a0);
            FDOT(hp2(wc,1), hp2(hp8,1), a1);
            FDOT(hp2(wc,2), hp2(hp8,2), a2);
            FDOT(hp2(wc,3), hp2(hp8,3), a3);
        }
        float av = (a0 + a1) + (a2 + a3);
        av += __shfl_xor(av, 1);
        av += __shfl_xor(av, 2);
        av += __shfl_xor(av, 4);
        __syncthreads();                                       // B5: rv_l ready
        float rd = rv_l[s * 64 + cc];
        float hv = tanhf(av + xp + rd + bhc);
        float g2 = zz + rd + hv;
        float o = hv * g2 / (1.f + __expf(-g2));
        if (q == 0) h_own[cc] = (_Float16)hv;
        __syncthreads();                                       // B6: h_own ready
        // wvp partials: rows 2*tid..+1 over own 64 k (h_own broadcast reads)
        half8 hr[8];
        #pragma unroll
        for (int kk = 0; kk < 8; kk++) hr[kk] = *(const half8*)(&h_own[kk * 8]);
        float w0 = 0.f, w1 = 0.f;
        #pragma unroll
        for (int kk = 0; kk < 8; kk++) {
            half8 h8 = hr[kk];
            #pragma unroll
            for (int pp = 0; pp < 4; pp++) {
                FDOT(hp2(wwr[0][kk],pp), hp2(h8,pp), w0);
                FDOT(hp2(wwr[1][kk],pp), hp2(h8,pp), w1);
            }
        }
        {   // publish wvp (packed f16 half2, 4B) + h slice into slot t&7
            PkW wq;
            wq.h = (half2_t){(_Float16)w0, (_Float16)w1};
            stw(&((u32*)(spub + R_WVP))[s * 512 + tid], wq.u, mall);
            if (tid < 8) {
                Pk2 u; u.h8 = *(const half8*)(&h_own[tid * 8]);
                u64* Hp = (u64*)(spub + R_H);
                stq(&Hp[s * 16 + tid * 2],     u.u[0], mall);
                stq(&Hp[s * 16 + tid * 2 + 1], u.u[1], mall);
            }
        }
        __syncthreads();                                       // B7: vmcnt drain (h + wvp)
        if (tid == 0) stsen(senrow, (u32)(t + 1));
        // deferred out store (off the sentinel critical path)
        if (q == 0) out[(size_t)(g * 512 + t) * 1024 + s * 64 + cc] = o;
    }
    // ================= finale: write h_tape_final (slice 0 of each group) =================
    if (s == 0) {
        #pragma unroll
        for (int n = 0; n < 16; n++)
            *(f32x2*)(&out[8388608ULL + (size_t)(g * 16 + n) * 1024 + tid * 2]) = tp[n];
    }
}

extern "C" void kernel_launch(void* const* d_in, const int* in_sizes, int n_in,
                              void* d_out, int out_size, void* d_ws, size_t ws_size,
                              hipStream_t stream) {
    const float* x     = (const float*)d_in[0];
    const float* tape0 = (const float*)d_in[1];
    const float* h0    = (const float*)d_in[2];
    const float* Wh    = (const float*)d_in[3];
    const float* Wxz   = (const float*)d_in[4];
    const float* bh    = (const float*)d_in[5];
    const float* Ww    = (const float*)d_in[6];

    char* ws = (char*)d_ws;
    _Float16* xbf   = (_Float16*)(ws + XBF_OFF);
    _Float16* wxzbf = (_Float16*)(ws + WXZ_OFF);
    _Float16* whbf  = (_Float16*)(ws + WH_OFF);
    _Float16* wwbf  = (_Float16*)(ws + WW_OFF);
    _Float16* xzbf  = (_Float16*)(ws + XZ_OFF);
    char* ring      = ws + RING_OFF;
    u32* vote       = (u32*)(ws + VOTE_OFF);
    u32* sen        = (u32*)(ws + SEN_OFF);

    // vote (4 KB) + sentinels (32 KB): zeroed every launch
    hipMemsetAsync(ws + VOTE_OFF, 0, 4096 + 32768, stream);

    cvt_kernel<<<8192, 256, 0, stream>>>(x, xbf, 2097152);
    cvt_kernel<<<2048, 256, 0, stream>>>(Wxz, wxzbf, 524288);
    cvt_kernel<<<1024, 256, 0, stream>>>(Wh, whbf, 262144);
    cvt_kernel<<<1024, 256, 0, stream>>>(Ww, wwbf, 262144);

    gemm_xz<<<dim3(16, 64), 256, 0, stream>>>(xbf, wxzbf, xzbf);

    scan_kernel<<<256, 512, 0, stream>>>(xzbf, tape0, h0, bh, whbf, wwbf,
                                         ring, sen, vote, (float*)d_out);
}